// Round 5
// baseline (328.035 us; speedup 1.0000x reference)
//
#include <hip/hip_runtime.h>

#define N_GRAPHS 100000
#define NTYPES 8
#define MAXD 128
#define FEAT 256
#define SPB 8              // 16-graph subtiles per block
#define GPB (16 * SPB)     // 128 graphs per block

typedef __attribute__((ext_vector_type(8))) short short8;
typedef __attribute__((ext_vector_type(4))) float f32x4;
typedef __attribute__((ext_vector_type(4))) unsigned uint4v;

// dims {16,32,64,128,64,32,16,128}; KS = ceil(dim/32) = {1,1,2,4,2,1,1,4}
constexpr int KSN[NTYPES]   = {1, 1, 2, 4, 2, 1, 1, 4};
constexpr int KSOFF[NTYPES] = {0, 1, 2, 4, 8, 10, 11, 12};   // prefix of KSN, total 16
constexpr int OFFC[NTYPES]  = {0, 32, 64, 128, 256, 320, 352, 384}; // col offset in concat
#define KTOT 16
#define LDA 524            // LDS row stride in shorts (16x524x2x2 = 33.5 KB)

__device__ __forceinline__ unsigned f2bf_u(float f) {
    unsigned u = __builtin_bit_cast(unsigned, f);
    return (u + 0x7fffu + ((u >> 16) & 1u)) >> 16;   // round-to-nearest-even
}
__device__ __forceinline__ unsigned cvt2(float lo, float hi) {
    return f2bf_u(lo) | (f2bf_u(hi) << 16);
}
__device__ __forceinline__ short8 cvt8(f32x4 a, f32x4 b) {
    uint4v u;
    u.x = cvt2(a.x, a.y); u.y = cvt2(a.z, a.w);
    u.z = cvt2(b.x, b.y); u.w = cvt2(b.z, b.w);
    return __builtin_bit_cast(short8, u);
}

// --- W -> bf16 fragment prepack. wp[(((t*16 + ct)*4 + ks)*4 + cgrp)*16 + c16]
//     = W[t][ct*16 + c16][ks*32 + cgrp*8 .. +7], zero-masked at k >= dim. 512 KB.
__global__ __launch_bounds__(256)
void prepack_w(const float* __restrict__ W, short8* __restrict__ wp)
{
    const int idx  = blockIdx.x * 256 + threadIdx.x;   // 32768
    const int c16  = idx & 15;
    const int cgrp = (idx >> 4) & 3;
    const int ks   = (idx >> 6) & 3;
    const int ct   = (idx >> 8) & 15;
    const int t    = (idx >> 12) & 7;
    const int col  = ct * 16 + c16;
    const int k    = ks * 32 + cgrp * 8;
    const int dim  = 16 << ((0x30123210u >> (4 * t)) & 0xf);
    const float* src = W + ((size_t)t * FEAT + col) * MAXD + k;
    f32x4 a = *(const f32x4*)src;
    f32x4 b = *(const f32x4*)(src + 4);
    #pragma unroll
    for (int j = 0; j < 4; ++j) {
        if (k + j     >= dim) a[j] = 0.f;
        if (k + 4 + j >= dim) b[j] = 0.f;
    }
    wp[idx] = cvt8(a, b);
}

// --- stage one 16-graph subtile: 16 rows x 512 concat-cols, f32->bf16->LDS ---
// 1024 threads: each wave stages one graph-row's 8 used-prefix segments.
__device__ __forceinline__ void stage16(const float* __restrict__ x, int gs,
                                        unsigned short (* __restrict__ As)[LDA], int tid)
{
    const int row = tid >> 6;       // 0..15
    const int c8  = tid & 63;       // elem8 index within concat row
    const int t = (c8 >= 4) + (c8 >= 8) + (c8 >= 16) + (c8 >= 32) +
                  (c8 >= 40) + (c8 >= 44) + (c8 >= 48);
    const int off8 = c8 < 4 ? 0 : c8 < 8 ? 4 : c8 < 16 ? 8 : c8 < 32 ? 16 :
                     c8 < 40 ? 32 : c8 < 44 ? 40 : c8 < 48 ? 44 : 48;
    const int k8 = c8 - off8;
    const float* rp = x + (((size_t)(gs + row)) * NTYPES + t) * MAXD + k8 * 8;
    f32x4 v0 = __builtin_nontemporal_load((const f32x4*)rp);
    f32x4 v1 = __builtin_nontemporal_load((const f32x4*)rp + 1);
    *(short8*)&As[row][c8 * 8] = cvt8(v0, v1);
}

template<int T, bool PRE>
__device__ __forceinline__ void load_bf(short8* __restrict__ Bf,
                                        const short8* __restrict__ wp,
                                        const float* __restrict__ W,
                                        int wave, int cgrp, int c16)
{
    if constexpr (PRE) {
        #pragma unroll
        for (int ks = 0; ks < KSN[T]; ++ks)
            Bf[KSOFF[T] + ks] = wp[(((T * 16 + wave) * 4 + ks) * 4 + cgrp) * 16 + c16];
    } else {
        constexpr int DIM = (T==0||T==6) ? 16 : (T==1||T==5) ? 32 : (T==2||T==4) ? 64 : 128;
        const int col = wave * 16 + c16;
        #pragma unroll
        for (int ks = 0; ks < KSN[T]; ++ks) {
            const int k = ks * 32 + cgrp * 8;
            const float* wf = W + ((size_t)T * FEAT + col) * MAXD + k;
            f32x4 a = *(const f32x4*)wf;
            f32x4 b = *(const f32x4*)(wf + 4);
            #pragma unroll
            for (int j = 0; j < 4; ++j) {
                if (k + j     >= DIM) a[j] = 0.f;
                if (k + 4 + j >= DIM) b[j] = 0.f;
            }
            Bf[KSOFF[T] + ks] = cvt8(a, b);
        }
    }
    if constexpr (T + 1 < NTYPES) load_bf<T + 1, PRE>(Bf, wp, W, wave, cgrp, c16);
}

template<int T>
__device__ __forceinline__ void compute_types(const short8* __restrict__ Bf,
                                              const unsigned short (* __restrict__ A)[LDA],
                                              float* __restrict__ out,
                                              const float* __restrict__ bias_g,
                                              int gs, int wave, int cgrp, int c16)
{
    f32x4 acc = {0.f, 0.f, 0.f, 0.f};
    #pragma unroll
    for (int ks = 0; ks < KSN[T]; ++ks) {
        short8 a = *(const short8*)&A[c16][OFFC[T] + ks * 32 + cgrp * 8];
        acc = __builtin_amdgcn_mfma_f32_16x16x32_bf16(a, Bf[KSOFF[T] + ks], acc, 0, 0, 0);
    }
    const int col = wave * 16 + c16;
    const float bv = bias_g[T * FEAT + col];
    #pragma unroll
    for (int r = 0; r < 4; ++r) {
        const int g = gs + cgrp * 4 + r;   // C/D: row = cgrp*4 + reg (m89 layout)
        __builtin_nontemporal_store(acc[r] + bv,
            &out[((size_t)g * NTYPES + T) * FEAT + col]);
    }
    if constexpr (T + 1 < NTYPES) compute_types<T + 1>(Bf, A, out, bias_g, gs, wave, cgrp, c16);
}

// 1024 threads = 16 waves; wave ct owns cols [ct*16, ct*16+16). All 8 types'
// B fragments live in 64 VGPR for the whole block. 16-graph supersteps write
// dense contiguous 128 KB output regions; A-tile LDS double-buffered.
template<bool PRE>
__global__ __launch_bounds__(1024, 4)
void node_enc(const float* __restrict__ x, const short8* __restrict__ wp,
              const float* __restrict__ W, const float* __restrict__ bias_g,
              float* __restrict__ out)
{
    __shared__ __align__(16) unsigned short As[2][16][LDA];
    const int tid  = threadIdx.x;
    const int lane = tid & 63;
    const int wave = tid >> 6;          // = col tile 0..15
    const int cgrp = lane >> 4;
    const int c16  = lane & 15;
    const int g0   = blockIdx.x * GPB;

    short8 Bf[KTOT];
    load_bf<0, PRE>(Bf, wp, W, wave, cgrp, c16);

    stage16(x, g0, As[0], tid);

    for (int s = 0; s < SPB; ++s) {
        const int gs = g0 + s * 16;
        if (gs >= N_GRAPHS) break;      // block-uniform
        __syncthreads();                // As[s&1] staged; prev reads of As[(s+1)&1] done
        const int gn = gs + 16;
        if (s + 1 < SPB && gn < N_GRAPHS)
            stage16(x, gn, As[(s + 1) & 1], tid);   // in flight during compute
        compute_types<0>(Bf, As[s & 1], out, bias_g, gs, wave, cgrp, c16);
    }
}

extern "C" void kernel_launch(void* const* d_in, const int* in_sizes, int n_in,
                              void* d_out, int out_size, void* d_ws, size_t ws_size,
                              hipStream_t stream)
{
    const float* x = (const float*)d_in[0];
    const float* W = (const float*)d_in[1];
    const float* b = (const float*)d_in[2];
    float* out = (float*)d_out;

    const int grid = (N_GRAPHS + GPB - 1) / GPB;           // 782
    const size_t wp_bytes = (size_t)32768 * sizeof(short8); // 512 KB

    if (ws_size >= wp_bytes) {
        short8* wp = (short8*)d_ws;
        prepack_w<<<128, 256, 0, stream>>>(W, wp);
        node_enc<true><<<grid, 1024, 0, stream>>>(x, wp, W, b, out);
    } else {
        node_enc<false><<<grid, 1024, 0, stream>>>(x, nullptr, W, b, out);
    }
}